// Round 4
// baseline (40.818 us; speedup 1.0000x reference)
//
#include <hip/hip_runtime.h>

// Problem constants (from reference setup_inputs)
#define NUM_VARS  256
#define NUM_NODES 65536
#define NUM_CATS  256
#define BATCH     512
#define NODES_PER_BLOCK 8   // 4 waves x 2 nodes/wave

typedef __attribute__((ext_vector_type(4))) float f32x4;
typedef __attribute__((ext_vector_type(4))) int   i32x4;

// out[node*BATCH + b] = log(params[s_pids[node] + data[vids[node]*BATCH + b]])
//
// Barrier-free per-wave design: wave w owns nodes {2w, 2w+1} of the block.
//  - Phase 1: each wave loads its 2 param rows (each row = one coalesced 1KiB
//    f32x4 wave-instruction), applies log to the 256-entry row (half the logs
//    vs logging the 512 gathered values), writes to its own LDS rows.
//  - Phase 2: reads data as int4 (coalesced), gathers from own LDS rows
//    (intra-wave dependency only -> no __syncthreads anywhere), streams f32x4
//    out via nontemporal stores.
__global__ __launch_bounds__(256) void input_layer_kernel(
    const int*   __restrict__ data,    // [NUM_VARS * BATCH] int32
    const float* __restrict__ params,  // [NUM_NODES * NUM_CATS]
    const int*   __restrict__ vids,    // [NUM_NODES]
    const int*   __restrict__ s_pids,  // [NUM_NODES]
    float*       __restrict__ out)     // [NUM_NODES * BATCH] fp32
{
    __shared__ float logp[NODES_PER_BLOCK * NUM_CATS];   // 8 KiB
    const int t    = threadIdx.x;
    const int w    = t >> 6;                             // wave 0..3
    const int lane = t & 63;
    const int gb   = blockIdx.x * NODES_PER_BLOCK;       // first node of block

    const int n0 = gb + 2 * w;                           // this wave's nodes
    const int n1 = n0 + 1;
    float* const row0 = &logp[(2 * w)     * NUM_CATS];
    float* const row1 = &logp[(2 * w + 1) * NUM_CATS];

    // ---- Phase 1: params rows -> log -> own LDS rows (no barrier needed) ----
    {
        const int c = lane * 4;                          // col 0..252 step 4
        const f32x4 p0 = __builtin_nontemporal_load(
            reinterpret_cast<const f32x4*>(&params[s_pids[n0] + c]));
        const f32x4 p1 = __builtin_nontemporal_load(
            reinterpret_cast<const f32x4*>(&params[s_pids[n1] + c]));
        f32x4 l0, l1;
        l0.x = __logf(p0.x); l0.y = __logf(p0.y); l0.z = __logf(p0.z); l0.w = __logf(p0.w);
        l1.x = __logf(p1.x); l1.y = __logf(p1.y); l1.z = __logf(p1.z); l1.w = __logf(p1.w);
        *reinterpret_cast<f32x4*>(&row0[c]) = l0;        // 16B/lane contiguous: conflict-free
        *reinterpret_cast<f32x4*>(&row1[c]) = l1;
    }

    // ---- Phase 2: gather + stream out (intra-wave dep only) ----
    const int vid0 = vids[n0];
    const int vid1 = vids[n1];
#pragma unroll
    for (int j = 0; j < 4; ++j) {
        const int   node = (j < 2) ? n0 : n1;
        const int   vid  = (j < 2) ? vid0 : vid1;
        float* const row = (j < 2) ? row0 : row1;
        const int   b    = (j & 1) * 256 + lane * 4;     // batch offset 0..508
        const i32x4 dv = *reinterpret_cast<const i32x4*>(&data[vid * BATCH + b]);
        f32x4 r;
        r.x = row[dv.x];
        r.y = row[dv.y];
        r.z = row[dv.z];
        r.w = row[dv.w];
        __builtin_nontemporal_store(r,
            reinterpret_cast<f32x4*>(&out[node * BATCH + b]));
    }
}

extern "C" void kernel_launch(void* const* d_in, const int* in_sizes, int n_in,
                              void* d_out, int out_size, void* d_ws, size_t ws_size,
                              hipStream_t stream) {
    const int*   data   = (const int*)d_in[0];
    const float* params = (const float*)d_in[1];
    const int*   vids   = (const int*)d_in[2];
    const int*   s_pids = (const int*)d_in[3];
    float*       out    = (float*)d_out;

    const int block = 256;
    const int grid  = NUM_NODES / NODES_PER_BLOCK;       // 8192 blocks, no tail
    input_layer_kernel<<<grid, block, 0, stream>>>(data, params, vids, s_pids, out);
}